// Round 3
// baseline (438.568 us; speedup 1.0000x reference)
//
#include <hip/hip_runtime.h>

#define TT 16384
#define CC 4096
#define NE 64
#define TOPK 2
#define ALPHA 0.01f
#define CSPLIT 4
#define KRANGE (CC / CSPLIT)   // 1024
#define BK 32                  // k per chunk
#define BT 128                 // tokens per workgroup
#define NCHUNK (KRANGE / BK)   // 32

// LDS layout (linear, global_load_lds-compatible), XOR-swizzled within each
// 32-float row at float4 granularity:
//   xs row t (128 rows): float4 slot q' holds global k-quad (q' ^ (t&7))
//   ws row e (64 rows):  float4 slot q' holds global k-quad (q' ^ (e>>3))
// Keys chosen so a wave's 8 address groups (tg&7 for x, eg for e) hit 8
// distinct bank-quads on ds_read_b128 -> conflict-free (T2, both-sides rule).

__device__ __forceinline__ void stage_chunk(const float* __restrict__ xg,   // x + t0*CC + k0 + kc*32
                                            const float* __restrict__ wg,   // w + k0 + kc*32
                                            float* __restrict__ xl,         // LDS x buffer (128*32 floats)
                                            float* __restrict__ wl,         // LDS w buffer (64*32 floats)
                                            int wv, int ln) {
    // x: 4 instrs/wave, 8 rows each (8 lanes/row, 16B/lane)
#pragma unroll
    for (int j = 0; j < 4; ++j) {
        const int r0  = wv * 32 + j * 8;
        const int row = r0 + (ln >> 3);
        const float* g = xg + (size_t)row * CC + (((ln & 7) ^ (ln >> 3)) << 2); // key = row&7 = ln>>3
        __builtin_amdgcn_global_load_lds((const __attribute__((address_space(1))) void*)g,
                                         (__attribute__((address_space(3))) void*)(xl + r0 * 32),
                                         16, 0, 0);
    }
    // w: 2 instrs/wave; key = row>>3 = wv*2 + j (uniform per instr)
#pragma unroll
    for (int j = 0; j < 2; ++j) {
        const int r0  = wv * 16 + j * 8;
        const int row = r0 + (ln >> 3);
        const float* g = wg + (size_t)row * CC + (((ln & 7) ^ (wv * 2 + j)) << 2);
        __builtin_amdgcn_global_load_lds((const __attribute__((address_space(1))) void*)g,
                                         (__attribute__((address_space(3))) void*)(wl + r0 * 32),
                                         16, 0, 0);
    }
}

__global__ __launch_bounds__(256, 2) void gate_gemm(const float* __restrict__ x,
                                                    const float* __restrict__ w,
                                                    float* __restrict__ part) {
    __shared__ float xs[2][BT * BK];   // 2 x 16 KB
    __shared__ float ws[2][NE * BK];   // 2 x 8 KB

    const int tile = blockIdx.x;
    const int cs   = blockIdx.y;
    const int t0   = tile * BT;
    const int k0   = cs * KRANGE;
    const int tid  = threadIdx.x;
    const int wv   = tid >> 6;   // wave 0..3
    const int ln   = tid & 63;   // lane
    const int tg   = tid >> 3;   // 0..31: tokens t0 + tg + 32*i
    const int eg   = tid & 7;    // 0..7:  experts eg*8 .. eg*8+7

    float acc[4][8];
#pragma unroll
    for (int i = 0; i < 4; ++i)
#pragma unroll
        for (int j = 0; j < 8; ++j) acc[i][j] = 0.f;

    const float* xb = x + (size_t)t0 * CC + k0;
    const float* wb = w + k0;

    // prologue: stage chunk 0 into buf 0
    stage_chunk(xb, wb, xs[0], ws[0], wv, ln);

    for (int kc = 0; kc < NCHUNK; ++kc) {
        // my prior stage's loads have landed in LDS
        asm volatile("s_waitcnt vmcnt(0)" ::: "memory");
        // all waves' loads landed; also guarantees prior compute's LDS reads done
        __builtin_amdgcn_s_barrier();
        __builtin_amdgcn_sched_barrier(0);   // no code motion across the barrier

        // issue next chunk's stage; flies under this chunk's FMA phase
        if (kc + 1 < NCHUNK)
            stage_chunk(xb + (kc + 1) * BK, wb + (kc + 1) * BK,
                        xs[(kc + 1) & 1], ws[(kc + 1) & 1], wv, ln);

        const float* __restrict__ xbuf = xs[kc & 1];
        const float* __restrict__ wbuf = ws[kc & 1];

#pragma unroll
        for (int kq = 0; kq < 8; ++kq) {
            float4 xq[4];
            const int xsw = ((kq ^ (tg & 7)) << 2);
#pragma unroll
            for (int i = 0; i < 4; ++i)
                xq[i] = *(const float4*)&xbuf[(tg + 32 * i) * BK + xsw];
            const int wsw = ((kq ^ eg) << 2);
#pragma unroll
            for (int j = 0; j < 8; ++j) {
                const float4 wq = *(const float4*)&wbuf[(eg * 8 + j) * BK + wsw];
#pragma unroll
                for (int i = 0; i < 4; ++i) {
                    acc[i][j] = fmaf(xq[i].x, wq.x, acc[i][j]);
                    acc[i][j] = fmaf(xq[i].y, wq.y, acc[i][j]);
                    acc[i][j] = fmaf(xq[i].z, wq.z, acc[i][j]);
                    acc[i][j] = fmaf(xq[i].w, wq.w, acc[i][j]);
                }
            }
        }
    }

    // epilogue: partial logits [cs][t][e]; t = t0 + tg + 32*i, e = eg*8 + j
    const int e0 = eg * 8;
#pragma unroll
    for (int i = 0; i < 4; ++i) {
        float* pb = part + (size_t)cs * TT * NE + (size_t)(t0 + tg + 32 * i) * NE + e0;
        *(float4*)(pb)     = make_float4(acc[i][0], acc[i][1], acc[i][2], acc[i][3]);
        *(float4*)(pb + 4) = make_float4(acc[i][4], acc[i][5], acc[i][6], acc[i][7]);
    }
}

// ---------------- finalize: reduce partials, softmax, top-2, Pi/count accumulation ----------------
__global__ __launch_bounds__(256) void finalize(const float* __restrict__ part,
                                                float* __restrict__ out,
                                                float* __restrict__ Pacc,
                                                float* __restrict__ Cacc) {
    __shared__ float Ps[NE];
    __shared__ float Csh[NE];
    const int tid = threadIdx.x;
    const int t   = blockIdx.x * 256 + tid;
    if (tid < NE) {
        Ps[tid]  = 0.f;
        Csh[tid] = 0.f;
    }
    __syncthreads();

    float l[NE];
#pragma unroll
    for (int e4 = 0; e4 < 16; ++e4) {
        const float4 v = *(const float4*)(part + (size_t)t * NE + e4 * 4);
        l[e4 * 4 + 0] = v.x;
        l[e4 * 4 + 1] = v.y;
        l[e4 * 4 + 2] = v.z;
        l[e4 * 4 + 3] = v.w;
    }
#pragma unroll
    for (int cs = 1; cs < CSPLIT; ++cs) {
#pragma unroll
        for (int e4 = 0; e4 < 16; ++e4) {
            const float4 v = *(const float4*)(part + (size_t)cs * TT * NE + (size_t)t * NE + e4 * 4);
            l[e4 * 4 + 0] += v.x;
            l[e4 * 4 + 1] += v.y;
            l[e4 * 4 + 2] += v.z;
            l[e4 * 4 + 3] += v.w;
        }
    }

    // top-2 scan (strict > keeps lowest index on ties, like lax.top_k)
    float m1 = -3.402823466e+38f, m2 = -3.402823466e+38f;
    int   i1 = 0, i2 = 0;
#pragma unroll
    for (int e = 0; e < NE; ++e) {
        const float v = l[e];
        if (v > m1) {
            m2 = m1; i2 = i1;
            m1 = v;  i1 = e;
        } else if (v > m2) {
            m2 = v; i2 = e;
        }
    }

    // softmax (max = m1)
    float s = 0.f;
#pragma unroll
    for (int e = 0; e < NE; ++e) {
        l[e] = expf(l[e] - m1);
        s += l[e];
    }
    const float inv = 1.f / s;

    // per-wave butterfly reduction of Pi (scores summed over the wave's 64 tokens)
    const int lane = tid & 63;
    float     myP  = 0.f;
#pragma unroll
    for (int e = 0; e < NE; ++e) {
        float r = l[e] * inv;
#pragma unroll
        for (int off = 32; off >= 1; off >>= 1) r += __shfl_xor(r, off, 64);
        if (lane == e) myP = r;
    }
    atomicAdd(&Ps[lane], myP);

    // expert selection counts
    atomicAdd(&Csh[i1], 1.f);
    atomicAdd(&Csh[i2], 1.f);

    // outputs: idx (as float) and normalized top-2 weights
    const float e2v = expf(m2 - m1);
    const float w1  = 1.f * inv;
    const float w2  = e2v * inv;
    const float iw  = 1.f / (w1 + w2);
    *(float2*)(out + (size_t)t * 2)                  = make_float2((float)i1, (float)i2);
    *(float2*)(out + (size_t)2 * TT + (size_t)t * 2) = make_float2(w1 * iw, w2 * iw);

    __syncthreads();
    if (tid < NE) {
        atomicAdd(&Pacc[tid], Ps[tid]);
        atomicAdd(&Cacc[tid], Csh[tid]);
    }
}

// ---------------- aux loss ----------------
__global__ void auxk(const float* __restrict__ Pacc, const float* __restrict__ Cacc,
                     float* __restrict__ out) {
    const int e  = threadIdx.x;
    const float Pi = Pacc[e] / (float)TT;
    const float fi = Cacc[e] * (float)NE / (float)(TT * TOPK);
    float v = Pi * fi;
#pragma unroll
    for (int off = 32; off >= 1; off >>= 1) v += __shfl_xor(v, off, 64);
    if (e == 0) out[(size_t)2 * TT * 2] = ALPHA * v;
}

extern "C" void kernel_launch(void* const* d_in, const int* in_sizes, int n_in,
                              void* d_out, int out_size, void* d_ws, size_t ws_size,
                              hipStream_t stream) {
    const float* x = (const float*)d_in[0];
    const float* w = (const float*)d_in[1];
    float* out  = (float*)d_out;
    float* part = (float*)d_ws;                        // CSPLIT*TT*NE floats = 16 MiB
    float* Pacc = part + (size_t)CSPLIT * TT * NE;     // 64 floats
    float* Cacc = Pacc + NE;                           // 64 floats

    hipMemsetAsync(Pacc, 0, 2 * NE * sizeof(float), stream);

    dim3 g1(TT / BT, CSPLIT);
    gate_gemm<<<g1, 256, 0, stream>>>(x, w, part);
    finalize<<<TT / 256, 256, 0, stream>>>(part, out, Pacc, Cacc);
    auxk<<<1, 64, 0, stream>>>(Pacc, Cacc, out);
}